// Round 13
// baseline (2039.837 us; speedup 1.0000x reference)
//
#include <hip/hip_runtime.h>

#define B_   8
#define N1_  8192
#define N2_  1024
#define K_   32
#define F1_  64
#define CIN_ 67
#define M1_  64
#define M2_  64
#define M3_  128
#define HSTR 40          // LDS activation row stride (floats)
#define FLTMAX 3.402823466e+38f

#define PB_  (B_*4)      // 32 producer blocks: 4 per batch, 2048 points each
#define PPTP 8           // producer points per thread (2048/256)

// order-preserving float->uint key (monotone incl. negatives; equal keys <=> equal bits)
__device__ __forceinline__ unsigned f2key(float f) {
  unsigned u = __float_as_uint(f);
  return u ^ ((unsigned)((int)u >> 31) | 0x80000000u);
}
__device__ __forceinline__ float readlane_f(float v, int l) {
  return __int_as_float(__builtin_amdgcn_readlane(__float_as_int(v), l));
}

// 6-step DPP wave64 reduce (row_shr 1/2/4/8 + row_bcast 15/31), broadcast via readlane(63).
__device__ __forceinline__ unsigned dpp_umax_bcast(unsigned v) {
  unsigned o;
  o = (unsigned)__builtin_amdgcn_update_dpp(0, (int)v, 0x111, 0xf, 0xf, false); v = v > o ? v : o;
  o = (unsigned)__builtin_amdgcn_update_dpp(0, (int)v, 0x112, 0xf, 0xf, false); v = v > o ? v : o;
  o = (unsigned)__builtin_amdgcn_update_dpp(0, (int)v, 0x114, 0xf, 0xf, false); v = v > o ? v : o;
  o = (unsigned)__builtin_amdgcn_update_dpp(0, (int)v, 0x118, 0xf, 0xf, false); v = v > o ? v : o;
  o = (unsigned)__builtin_amdgcn_update_dpp(0, (int)v, 0x142, 0xf, 0xf, false); v = v > o ? v : o;
  o = (unsigned)__builtin_amdgcn_update_dpp(0, (int)v, 0x143, 0xf, 0xf, false); v = v > o ? v : o;
  return (unsigned)__builtin_amdgcn_readlane((int)v, 63);
}
__device__ __forceinline__ unsigned dpp_umin_bcast(unsigned v) {
  unsigned o;
  o = (unsigned)__builtin_amdgcn_update_dpp(-1, (int)v, 0x111, 0xf, 0xf, false); v = v < o ? v : o;
  o = (unsigned)__builtin_amdgcn_update_dpp(-1, (int)v, 0x112, 0xf, 0xf, false); v = v < o ? v : o;
  o = (unsigned)__builtin_amdgcn_update_dpp(-1, (int)v, 0x114, 0xf, 0xf, false); v = v < o ? v : o;
  o = (unsigned)__builtin_amdgcn_update_dpp(-1, (int)v, 0x118, 0xf, 0xf, false); v = v < o ? v : o;
  o = (unsigned)__builtin_amdgcn_update_dpp(-1, (int)v, 0x142, 0xf, 0xf, false); v = v < o ? v : o;
  o = (unsigned)__builtin_amdgcn_update_dpp(-1, (int)v, 0x143, 0xf, 0xf, false); v = v < o ? v : o;
  return (unsigned)__builtin_amdgcn_readlane((int)v, 63);
}

// handshake encode: coords in [0,1) -> bits in [0xC0000000, 0xFF7FFFFF]; never 0x0 (memset) or 0xAAAAAAAA (poison)
#define HS_ENC(f) (__float_as_uint(f) ^ 0xC0000000u)
#define HS_DEC(u) __uint_as_float((u) ^ 0xC0000000u)

__global__ __launch_bounds__(256, 1) void fused_kernel(
    const float* __restrict__ xyz, const float* __restrict__ feat,
    const float* __restrict__ w0g, const float* __restrict__ b0g,
    const float* __restrict__ w1g, const float* __restrict__ b1g,
    const float* __restrict__ w2g, const float* __restrict__ b2g,
    float* __restrict__ out_xyz, float* __restrict__ out_feat,
    unsigned long long* __restrict__ slots)
{
  __shared__ float4 wslot[4];                       // fps per-wave local winners
  __shared__ float4 gwin;                           // fps global winner broadcast
  __shared__ __align__(16) float buf0[CIN_*HSTR];   // consumer activations
  __shared__ __align__(16) float buf1[M1_*HSTR];
  __shared__ float sval[2][4];
  __shared__ int   sidx[2][4];
  __shared__ float qsh[3];

  const int t = threadIdx.x;
  const int lane = t & 63;
  const int wv_ = t >> 6;

  if (blockIdx.x < PB_) {
    // ============ FPS producer: 4 blocks per batch, stamped-qword cross-block exchange ============
    __builtin_amdgcn_s_setprio(3);
    const int b = blockIdx.x >> 2, s = blockIdx.x & 3;
    const float* gxyz = xyz + (size_t)b * (N1_ * 3);
    float* oxyz = out_xyz + (size_t)b * (N2_ * 3);

    float x[PPTP], y[PPTP], z[PPTP], md[PPTP];
    {
      const float4* gs = (const float4*)gxyz;
#pragma unroll
      for (int w = 0; w < 6; ++w) {
        const float4 v = gs[s * 1536 + t * 6 + w];
#pragma unroll
        for (int c = 0; c < 4; ++c) {
          const int p = w * 4 + c;               // flat float index 0..23 within thread chunk
          const float val = (c == 0) ? v.x : (c == 1) ? v.y : (c == 2) ? v.z : v.w;
          const int j = p / 3, cc = p % 3;
          if (cc == 0) x[j] = val; else if (cc == 1) y[j] = val; else z[j] = val;
        }
      }
    }
#pragma unroll
    for (int j = 0; j < PPTP; ++j) md[j] = FLTMAX;  // matches jnp.finfo(float32).max init

    float px = gxyz[0], py = gxyz[1], pz = gxyz[2]; // winner 0 = point 0 (exact f32)

    for (int i = 0;; ++i) {
      if (s == 0 && t == 0) {
        const int o = i * 3;
        oxyz[o] = px; oxyz[o+1] = py; oxyz[o+2] = pz;
        unsigned* hs = (unsigned*)(out_feat + (size_t)((b << 10) + i) * M3_);
        atomicExch(&hs[0], HS_ENC(px));
        atomicExch(&hs[1], HS_ENC(py));
        atomicExch(&hs[2], HS_ENC(pz));
      }
      if (i == N2_ - 1) break;

      // fused distance update + first-max argmax with inline coord tracking
      float bestv, bx, by, bz;
#pragma unroll
      for (int j = 0; j < PPTP; ++j) {
        const float dx = __fsub_rn(x[j], px);
        const float dy = __fsub_rn(y[j], py);
        const float dz = __fsub_rn(z[j], pz);
        const float d  = __fadd_rn(__fadd_rn(__fmul_rn(dx,dx), __fmul_rn(dy,dy)), __fmul_rn(dz,dz));
        md[j] = fminf(md[j], d);
        if (j == 0) { bestv = md[0]; bx = x[0]; by = y[0]; bz = z[0]; }
        else {
          const bool c = md[j] > bestv;
          bestv = c ? md[j] : bestv;
          bx = c ? x[j] : bx; by = c ? y[j] : by; bz = c ? z[j] : bz;
        }
      }
      // wave winner via DPP max + ballot (lowest lane = lowest point index)
      {
        const unsigned key = f2key(bestv);
        const unsigned kmax = dpp_umax_bcast(key);
        const int fl = __ffsll(__ballot(key == kmax)) - 1;
        if (lane == fl) {
          float4 sl; sl.x = bestv; sl.y = bx; sl.z = by; sl.w = bz;
          wslot[wv_] = sl;
        }
      }
      __syncthreads();

      if (wv_ == 0) {
        // block-local winner: scan 4 wave slots (ascending wave, strict > = lowest index on ties)
        float4 wb = wslot[0];
#pragma unroll
        for (int u = 1; u < 4; ++u) { const float4 sl = wslot[u]; if (sl.x > wb.x) wb = sl; }
        const unsigned long long st = ((unsigned long long)(unsigned)(i + 1)) << 32;
        if (t == 0) {   // publish: 4 self-validating stamped qwords, no fence needed
          unsigned long long* sl = slots + (((b * 2 + ((i + 1) & 1)) * 4 + s) << 2);
          atomicExch(&sl[0], st | __float_as_uint(wb.x));
          atomicExch(&sl[1], st | __float_as_uint(wb.y));
          atomicExch(&sl[2], st | __float_as_uint(wb.z));
          atomicExch(&sl[3], st | __float_as_uint(wb.w));
        }
        float fv, fx, fy, fz;
        if (t < 4) {    // lane L polls block L's slot
          unsigned long long* sl = slots + (((b * 2 + ((i + 1) & 1)) * 4 + t) << 2);
          const unsigned sw = (unsigned)(i + 1);
          unsigned long long q;
          do { q = atomicOr(&sl[0], 0ull); } while ((unsigned)(q >> 32) != sw);
          fv = __uint_as_float((unsigned)q);
          do { q = atomicOr(&sl[1], 0ull); } while ((unsigned)(q >> 32) != sw);
          fx = __uint_as_float((unsigned)q);
          do { q = atomicOr(&sl[2], 0ull); } while ((unsigned)(q >> 32) != sw);
          fy = __uint_as_float((unsigned)q);
          do { q = atomicOr(&sl[3], 0ull); } while ((unsigned)(q >> 32) != sw);
          fz = __uint_as_float((unsigned)q);
        }
        // combine 4 block winners (ascending s, strict > = lowest point index on ties)
        float bv = readlane_f(fv, 0), cx = readlane_f(fx, 0), cy = readlane_f(fy, 0), cz = readlane_f(fz, 0);
#pragma unroll
        for (int u = 1; u < 4; ++u) {
          const float vv = readlane_f(fv, u);
          if (vv > bv) { bv = vv; cx = readlane_f(fx, u); cy = readlane_f(fy, u); cz = readlane_f(fz, u); }
        }
        if (t == 0) { float4 g; g.x = cx; g.y = cy; g.z = cz; g.w = bv; gwin = g; }
      }
      __syncthreads();
      px = gwin.x; py = gwin.y; pz = gwin.z;
    }
    return;
  }

  // ================= KNN + MLP + maxpool consumer: one 256-thread block per query (R11-proven) =================
  const int bq = blockIdx.x - PB_;
  const int b  = bq >> 10;
  const float* gxyz = xyz + (size_t)b * (N1_ * 3);

  if (t == 0) {
    unsigned* hs = (unsigned*)(out_feat + (size_t)bq * M3_);
#pragma unroll
    for (int w = 0; w < 3; ++w) {
      unsigned v;
      do { __builtin_amdgcn_s_sleep(2); v = atomicOr(&hs[w], 0u); }
      while (v == 0u || v == 0xAAAAAAAAu);
      qsh[w] = HS_DEC(v);
    }
  }
  __syncthreads();
  const float qx = qsh[0], qy = qsh[1], qz = qsh[2];
  const float q2 = __fadd_rn(__fadd_rn(__fmul_rn(qx,qx), __fmul_rn(qy,qy)), __fmul_rn(qz,qz));

  // d2 = (q2 + p2) - 2*qp (reference op order) into registers; inline top-2 (lowest-idx ties)
  float d2v[32];
  float m1 = FLTMAX, m2 = FLTMAX; int i1 = t*32, i2 = t*32;
  {
    const float4* gs = (const float4*)gxyz;
#pragma unroll
    for (int g8 = 0; g8 < 4; ++g8) {
      float f[24];
#pragma unroll
      for (int w = 0; w < 6; ++w) {
        const float4 v = gs[t * 24 + g8 * 6 + w];
        f[w*4+0] = v.x; f[w*4+1] = v.y; f[w*4+2] = v.z; f[w*4+3] = v.w;
      }
#pragma unroll
      for (int m = 0; m < 8; ++m) {
        const int j = g8 * 8 + m;
        const float px = f[3*m], py = f[3*m+1], pz = f[3*m+2];
        const float p2 = __fadd_rn(__fadd_rn(__fmul_rn(px,px), __fmul_rn(py,py)), __fmul_rn(pz,pz));
        const float qp = __fadd_rn(__fadd_rn(__fmul_rn(qx,px), __fmul_rn(qy,py)), __fmul_rn(qz,pz));
        const float d  = __fsub_rn(__fadd_rn(q2, p2), __fmul_rn(2.0f, qp));
        d2v[j] = d;
        const int idx = t*32 + j;
        const bool c1 = d < m1;
        const bool c2 = d < m2;
        const float nm2 = c1 ? m1 : (c2 ? d : m2);
        const int   ni2 = c1 ? i1 : (c2 ? idx : i2);
        m1 = c1 ? d : m1; i1 = c1 ? idx : i1;
        m2 = nm2; i2 = ni2;
      }
    }
  }

  // top-32: 1 barrier/round; DPP min; extraction promotes cached 2nd-min, rescan only if stale
  int myk_idx = 0; float myk_d = 0.0f; int k0_idx = 0;
  unsigned removed = 0u; bool have2 = true;
  for (int kk = 0; kk < K_; ++kk) {
    const int p = kk & 1;
    const unsigned key = f2key(m1);
    const unsigned kmin = dpp_umin_bcast(key);
    const int fl = __ffsll(__ballot(key == kmin)) - 1;
    if (lane == fl) { sval[p][t >> 6] = m1; sidx[p][t >> 6] = i1; }
    __syncthreads();
    float wv = sval[p][0]; int wi = sidx[p][0];
#pragma unroll
    for (int u = 1; u < 4; ++u) {
      const float v = sval[p][u]; const int ii = sidx[p][u];
      if (v < wv || (v == wv && ii < wi)) { wv = v; wi = ii; }
    }
    wi &= (N1_ - 1);
    if ((t >> 3) == kk) { myk_idx = wi; myk_d = wv; }
    if (kk == 0) k0_idx = wi;
    if (kk < K_ - 1 && t == (wi >> 5)) {
      removed |= 1u << (wi & 31);
      if (have2) { m1 = m2; i1 = i2; have2 = false; }
      else {
        m1 = FLTMAX; i1 = t*32; m2 = FLTMAX; i2 = t*32;
#pragma unroll
        for (int j = 0; j < 32; ++j) {
          const float d = ((removed >> j) & 1u) ? FLTMAX : d2v[j];
          const int idx = t*32 + j;
          const bool c1 = d < m1;
          const bool c2 = d < m2;
          const float nm2 = c1 ? m1 : (c2 ? d : m2);
          const int   ni2 = c1 ? i1 : (c2 ? idx : i2);
          m1 = c1 ? d : m1; i1 = c1 ? idx : i1;
          m2 = nm2; i2 = ni2;
        }
        have2 = true;
      }
    }
  }

  // -------- phase 2: gather h0, MLP (weights direct from global/L1), maxpool --------
  {
    const int k = t >> 3, fg = t & 7;
    int nk = myk_idx;
    if (myk_d > 0.04f) nk = k0_idx;        // ball-query radius clamp
    nk &= (N1_ - 1);
    const float* frow = feat + ((size_t)(b * N1_ + nk)) * F1_ + fg * 8;
    const float4 f0 = *(const float4*)frow;
    const float4 f1 = *(const float4*)(frow + 4);
    const int fb = 3 + fg * 8;
    buf0[(fb+0)*HSTR + k] = f0.x;
    buf0[(fb+1)*HSTR + k] = f0.y;
    buf0[(fb+2)*HSTR + k] = f0.z;
    buf0[(fb+3)*HSTR + k] = f0.w;
    buf0[(fb+4)*HSTR + k] = f1.x;
    buf0[(fb+5)*HSTR + k] = f1.y;
    buf0[(fb+6)*HSTR + k] = f1.z;
    buf0[(fb+7)*HSTR + k] = f1.w;
    if (fg < 3) {
      const float pc = gxyz[(size_t)nk * 3 + fg];
      const float qc = (fg == 0) ? qx : (fg == 1) ? qy : qz;
      buf0[fg * HSTR + k] = __fsub_rn(pc, qc);
    }
  }
  __syncthreads();

#define LEAKY_STORE2(acc, mi_, biasg, hout) { \
    const float bb = biasg[mg*2 + (mi_)]; \
    float4 v; \
    v.x = acc.x + bb; v.x = fmaxf(v.x, 0.2f*v.x); \
    v.y = acc.y + bb; v.y = fmaxf(v.y, 0.2f*v.y); \
    v.z = acc.z + bb; v.z = fmaxf(v.z, 0.2f*v.z); \
    v.w = acc.w + bb; v.w = fmaxf(v.w, 0.2f*v.w); \
    *(float4*)&hout[(mg*2 + (mi_)) * HSTR + kq * 4] = v; }

  // layer 1: 67 -> 64 (all 256 threads: 2m x 4k tiles; ascending-c order)
  {
    const int kq = t & 7, mg = t >> 3;   // mg 0..31
    float4 a0 = {0,0,0,0}, a1 = {0,0,0,0};
#pragma unroll 4
    for (int c = 0; c < CIN_; ++c) {
      const float2 wp = *(const float2*)&w0g[c * M1_ + mg * 2];
      const float4 h  = *(const float4*)&buf0[c * HSTR + kq * 4];
      a0.x += h.x*wp.x; a0.y += h.y*wp.x; a0.z += h.z*wp.x; a0.w += h.w*wp.x;
      a1.x += h.x*wp.y; a1.y += h.y*wp.y; a1.z += h.z*wp.y; a1.w += h.w*wp.y;
    }
    LEAKY_STORE2(a0, 0, b0g, buf1) LEAKY_STORE2(a1, 1, b0g, buf1)
  }
  __syncthreads();

  // layer 2: 64 -> 64
  {
    const int kq = t & 7, mg = t >> 3;
    float4 a0 = {0,0,0,0}, a1 = {0,0,0,0};
#pragma unroll 4
    for (int c = 0; c < M1_; ++c) {
      const float2 wp = *(const float2*)&w1g[c * M2_ + mg * 2];
      const float4 h  = *(const float4*)&buf1[c * HSTR + kq * 4];
      a0.x += h.x*wp.x; a0.y += h.y*wp.x; a0.z += h.z*wp.x; a0.w += h.w*wp.x;
      a1.x += h.x*wp.y; a1.y += h.y*wp.y; a1.z += h.z*wp.y; a1.w += h.w*wp.y;
    }
    LEAKY_STORE2(a0, 0, b1g, buf0) LEAKY_STORE2(a1, 1, b1g, buf0)
  }
#undef LEAKY_STORE2
  __syncthreads();

  // layer 3: 64 -> 128, + maxpool over k
  {
    const int kq = t & 7, mg = t >> 3;   // mg in 0..31
    float4 a0 = {0,0,0,0}, a1 = {0,0,0,0}, a2 = {0,0,0,0}, a3 = {0,0,0,0};
#pragma unroll 4
    for (int c = 0; c < M2_; ++c) {
      const float4 wp = *(const float4*)&w2g[c * M3_ + mg * 4];
      const float4 h  = *(const float4*)&buf0[c * HSTR + kq * 4];
      a0.x += h.x*wp.x; a0.y += h.y*wp.x; a0.z += h.z*wp.x; a0.w += h.w*wp.x;
      a1.x += h.x*wp.y; a1.y += h.y*wp.y; a1.z += h.z*wp.y; a1.w += h.w*wp.y;
      a2.x += h.x*wp.z; a2.y += h.y*wp.z; a2.z += h.z*wp.z; a2.w += h.w*wp.z;
      a3.x += h.x*wp.w; a3.y += h.y*wp.w; a3.z += h.z*wp.w; a3.w += h.w*wp.w;
    }
    float vm[4];
#define BIAS_LEAKY_HMAX(acc, mi_) { \
      const float bb = b2g[mg*4 + (mi_)]; \
      float vx = acc.x + bb; vx = fmaxf(vx, 0.2f*vx); \
      float vy = acc.y + bb; vy = fmaxf(vy, 0.2f*vy); \
      float vz = acc.z + bb; vz = fmaxf(vz, 0.2f*vz); \
      float vw = acc.w + bb; vw = fmaxf(vw, 0.2f*vw); \
      vm[mi_] = fmaxf(fmaxf(vx, vy), fmaxf(vz, vw)); }
    BIAS_LEAKY_HMAX(a0, 0) BIAS_LEAKY_HMAX(a1, 1) BIAS_LEAKY_HMAX(a2, 2) BIAS_LEAKY_HMAX(a3, 3)
#undef BIAS_LEAKY_HMAX
#pragma unroll
    for (int m = 1; m <= 4; m <<= 1) {
      vm[0] = fmaxf(vm[0], __shfl_xor(vm[0], m, 64));
      vm[1] = fmaxf(vm[1], __shfl_xor(vm[1], m, 64));
      vm[2] = fmaxf(vm[2], __shfl_xor(vm[2], m, 64));
      vm[3] = fmaxf(vm[3], __shfl_xor(vm[3], m, 64));
    }
    if (kq == 0) {
      float4 o; o.x = vm[0]; o.y = vm[1]; o.z = vm[2]; o.w = vm[3];
      *(float4*)&out_feat[(size_t)bq * M3_ + mg * 4] = o;   // overwrites this query's handshake words
    }
  }
}

extern "C" void kernel_launch(void* const* d_in, const int* in_sizes, int n_in,
                              void* d_out, int out_size, void* d_ws, size_t ws_size,
                              hipStream_t stream) {
  const float* xyz  = (const float*)d_in[0];
  const float* feat = (const float*)d_in[1];
  const float* w0   = (const float*)d_in[2];
  const float* b0   = (const float*)d_in[3];
  const float* w1   = (const float*)d_in[4];
  const float* b1   = (const float*)d_in[5];
  const float* w2   = (const float*)d_in[6];
  const float* b2   = (const float*)d_in[7];

  float* out_xyz  = (float*)d_out;                  // (8,1024,3) f32
  float* out_feat = out_xyz + B_ * N2_ * 3;         // (8,1024,128) f32
  unsigned long long* slots = (unsigned long long*)d_ws;  // 8*2*4 slots x 4 qwords = 2 KB

  fused_kernel<<<PB_ + B_ * N2_, 256, 0, stream>>>(xyz, feat, w0, b0, w1, b1, w2, b2,
                                                   out_xyz, out_feat, slots);
}

// Round 14
// 1531.451 us; speedup vs baseline: 1.3320x; 1.3320x over previous
//
#include <hip/hip_runtime.h>

#define B_   8
#define N1_  8192
#define N2_  1024
#define K_   32
#define F1_  64
#define CIN_ 67
#define M1_  64
#define M2_  64
#define M3_  128
#define HSTR 40          // LDS activation row stride (floats)
#define FLTMAX 3.402823466e+38f

#define PPT  32          // producer points per thread (8192/256)

// order-preserving float->uint key (monotone incl. negatives; equal keys <=> equal bits)
__device__ __forceinline__ unsigned f2key(float f) {
  unsigned u = __float_as_uint(f);
  return u ^ ((unsigned)((int)u >> 31) | 0x80000000u);
}
__device__ __forceinline__ float readlane_f(float v, int l) {
  return __int_as_float(__builtin_amdgcn_readlane(__float_as_int(v), l));
}

// 6-step DPP wave64 reduce (row_shr 1/2/4/8 + row_bcast 15/31), broadcast via readlane(63).
__device__ __forceinline__ unsigned dpp_umax_bcast(unsigned v) {
  unsigned o;
  o = (unsigned)__builtin_amdgcn_update_dpp(0, (int)v, 0x111, 0xf, 0xf, false); v = v > o ? v : o;
  o = (unsigned)__builtin_amdgcn_update_dpp(0, (int)v, 0x112, 0xf, 0xf, false); v = v > o ? v : o;
  o = (unsigned)__builtin_amdgcn_update_dpp(0, (int)v, 0x114, 0xf, 0xf, false); v = v > o ? v : o;
  o = (unsigned)__builtin_amdgcn_update_dpp(0, (int)v, 0x118, 0xf, 0xf, false); v = v > o ? v : o;
  o = (unsigned)__builtin_amdgcn_update_dpp(0, (int)v, 0x142, 0xf, 0xf, false); v = v > o ? v : o;
  o = (unsigned)__builtin_amdgcn_update_dpp(0, (int)v, 0x143, 0xf, 0xf, false); v = v > o ? v : o;
  return (unsigned)__builtin_amdgcn_readlane((int)v, 63);
}
__device__ __forceinline__ unsigned dpp_umin_bcast(unsigned v) {
  unsigned o;
  o = (unsigned)__builtin_amdgcn_update_dpp(-1, (int)v, 0x111, 0xf, 0xf, false); v = v < o ? v : o;
  o = (unsigned)__builtin_amdgcn_update_dpp(-1, (int)v, 0x112, 0xf, 0xf, false); v = v < o ? v : o;
  o = (unsigned)__builtin_amdgcn_update_dpp(-1, (int)v, 0x114, 0xf, 0xf, false); v = v < o ? v : o;
  o = (unsigned)__builtin_amdgcn_update_dpp(-1, (int)v, 0x118, 0xf, 0xf, false); v = v < o ? v : o;
  o = (unsigned)__builtin_amdgcn_update_dpp(-1, (int)v, 0x142, 0xf, 0xf, false); v = v < o ? v : o;
  o = (unsigned)__builtin_amdgcn_update_dpp(-1, (int)v, 0x143, 0xf, 0xf, false); v = v < o ? v : o;
  return (unsigned)__builtin_amdgcn_readlane((int)v, 63);
}

// handshake encode: coords in [0,1) -> bits in [0xC0000000, 0xFF7FFFFF]; never 0x0 (memset) or 0xAAAAAAAA (poison)
#define HS_ENC(f) (__float_as_uint(f) ^ 0xC0000000u)
#define HS_DEC(u) __uint_as_float((u) ^ 0xC0000000u)

__global__ __launch_bounds__(256, 1) void fused_kernel(
    const float* __restrict__ xyz, const float* __restrict__ feat,
    const float* __restrict__ w0g, const float* __restrict__ b0g,
    const float* __restrict__ w1g, const float* __restrict__ b1g,
    const float* __restrict__ w2g, const float* __restrict__ b2g,
    float* __restrict__ out_xyz, float* __restrict__ out_feat)
{
  __shared__ __align__(16) float buf0[CIN_*HSTR];   // consumer activations / producer slot area
  __shared__ __align__(16) float buf1[M1_*HSTR];
  __shared__ float sval[2][4];
  __shared__ int   sidx[2][4];
  __shared__ float qsh[3];

  const int t = threadIdx.x;
  const int lane = t & 63;
  const int wv_ = t >> 6;

  if (blockIdx.x < B_) {
    // ===== FPS producer: barrier-free stamped-LDS exchange between the 4 waves =====
    __builtin_amdgcn_s_setprio(3);
    const int b = blockIdx.x;
    const float* gxyz = xyz + (size_t)b * (N1_ * 3);
    float* oxyz = out_xyz + (size_t)b * (N2_ * 3);

    float4* pslot = (float4*)buf0;                       // 8 payload slots (2 parities x 4 waves)
    volatile int* pstamp = (volatile int*)(buf0 + 32);   // 8 stamps, after the 128B of slots

    if (t < 8) pstamp[t] = 0;

    float x[PPT], y[PPT], z[PPT], md[PPT];
    {
      const float4* gs = (const float4*)gxyz;
#pragma unroll
      for (int w = 0; w < 24; ++w) {
        const float4 v = gs[t * 24 + w];
#pragma unroll
        for (int c = 0; c < 4; ++c) {
          const int p = w * 4 + c;               // flat float index 0..95 -> 32 contiguous points
          const float val = (c == 0) ? v.x : (c == 1) ? v.y : (c == 2) ? v.z : v.w;
          const int j = p / 3, cc = p % 3;
          if (cc == 0) x[j] = val; else if (cc == 1) y[j] = val; else z[j] = val;
        }
      }
    }
#pragma unroll
    for (int j = 0; j < PPT; ++j) md[j] = FLTMAX;  // matches jnp.finfo(float32).max init
    __syncthreads();                                // one-time: stamp init visible to all waves

    float px = gxyz[0], py = gxyz[1], pz = gxyz[2]; // winner 0 = point 0 (exact f32)
    if (t == 0) {
      oxyz[0] = px; oxyz[1] = py; oxyz[2] = pz;
      unsigned* hs = (unsigned*)(out_feat + (size_t)(b << 10) * M3_);
      atomicExch(&hs[0], HS_ENC(px));
      atomicExch(&hs[1], HS_ENC(py));
      atomicExch(&hs[2], HS_ENC(pz));
    }

    for (int i = 1; i < N2_; ++i) {
      // fused distance update + first-max argmax with inline coord tracking
      float bestv, bx, by, bz;
#pragma unroll
      for (int j = 0; j < PPT; ++j) {
        const float dx = __fsub_rn(x[j], px);
        const float dy = __fsub_rn(y[j], py);
        const float dz = __fsub_rn(z[j], pz);
        const float d  = __fadd_rn(__fadd_rn(__fmul_rn(dx,dx), __fmul_rn(dy,dy)), __fmul_rn(dz,dz));
        md[j] = fminf(md[j], d);
        if (j == 0) { bestv = md[0]; bx = x[0]; by = y[0]; bz = z[0]; }
        else {
          const bool c = md[j] > bestv;
          bestv = c ? md[j] : bestv;
          bx = c ? x[j] : bx; by = c ? y[j] : by; bz = c ? z[j] : bz;
        }
      }
      // wave winner via DPP max + ballot (lowest lane = lowest point index)
      const unsigned key = f2key(bestv);
      const unsigned kmax = dpp_umax_bcast(key);
      const int fl = __ffsll(__ballot(key == kmax)) - 1;
      const int par = (i & 1) * 4;
      if (lane == fl) {
        float4 pl; pl.x = bestv; pl.y = bx; pl.z = by; pl.w = bz;
        pslot[par + wv_] = pl;       // payload first (DS pipe in-order per wave)
        pstamp[par + wv_] = i;       // stamp last => stamp visible implies payload visible
      }
      // poll: lane L waits on slot (L&3); SIMT reconvergence = all 4 slots ready
      const int sb = par + (lane & 3);
      while (pstamp[sb] != i) { }
      volatile float* pf = (volatile float*)&pslot[sb];
      const float vv = pf[0], vx = pf[1], vy = pf[2], vz = pf[3];
      // combine 4 wave winners (ascending wave = ascending point range; strict > keeps lowest)
      const float c0 = readlane_f(vv, 0), c1 = readlane_f(vv, 1);
      const float c2 = readlane_f(vv, 2), c3 = readlane_f(vv, 3);
      int ws = 0; float bv = c0;
      if (c1 > bv) { bv = c1; ws = 1; }
      if (c2 > bv) { bv = c2; ws = 2; }
      if (c3 > bv) { bv = c3; ws = 3; }
      px = readlane_f(vx, ws); py = readlane_f(vy, ws); pz = readlane_f(vz, ws);
      if (t == 0) {   // fire-and-forget publish (no barrier => no vmcnt drain on critical path)
        const int o = i * 3;
        oxyz[o] = px; oxyz[o+1] = py; oxyz[o+2] = pz;
        unsigned* hs = (unsigned*)(out_feat + (size_t)((b << 10) + i) * M3_);
        atomicExch(&hs[0], HS_ENC(px));
        atomicExch(&hs[1], HS_ENC(py));
        atomicExch(&hs[2], HS_ENC(pz));
      }
    }
    return;
  }

  // ================= KNN + MLP + maxpool consumer: one 256-thread block per query (R11-proven) =================
  const int bq = blockIdx.x - B_;
  const int b  = bq >> 10;
  const float* gxyz = xyz + (size_t)b * (N1_ * 3);

  if (t == 0) {
    unsigned* hs = (unsigned*)(out_feat + (size_t)bq * M3_);
#pragma unroll
    for (int w = 0; w < 3; ++w) {
      unsigned v;
      do { __builtin_amdgcn_s_sleep(2); v = atomicOr(&hs[w], 0u); }
      while (v == 0u || v == 0xAAAAAAAAu);
      qsh[w] = HS_DEC(v);
    }
  }
  __syncthreads();
  const float qx = qsh[0], qy = qsh[1], qz = qsh[2];
  const float q2 = __fadd_rn(__fadd_rn(__fmul_rn(qx,qx), __fmul_rn(qy,qy)), __fmul_rn(qz,qz));

  // d2 = (q2 + p2) - 2*qp (reference op order) into registers; inline top-2 (lowest-idx ties)
  float d2v[32];
  float m1 = FLTMAX, m2 = FLTMAX; int i1 = t*32, i2 = t*32;
  {
    const float4* gs = (const float4*)gxyz;
#pragma unroll
    for (int g8 = 0; g8 < 4; ++g8) {
      float f[24];
#pragma unroll
      for (int w = 0; w < 6; ++w) {
        const float4 v = gs[t * 24 + g8 * 6 + w];
        f[w*4+0] = v.x; f[w*4+1] = v.y; f[w*4+2] = v.z; f[w*4+3] = v.w;
      }
#pragma unroll
      for (int m = 0; m < 8; ++m) {
        const int j = g8 * 8 + m;
        const float px = f[3*m], py = f[3*m+1], pz = f[3*m+2];
        const float p2 = __fadd_rn(__fadd_rn(__fmul_rn(px,px), __fmul_rn(py,py)), __fmul_rn(pz,pz));
        const float qp = __fadd_rn(__fadd_rn(__fmul_rn(qx,px), __fmul_rn(qy,py)), __fmul_rn(qz,pz));
        const float d  = __fsub_rn(__fadd_rn(q2, p2), __fmul_rn(2.0f, qp));
        d2v[j] = d;
        const int idx = t*32 + j;
        const bool c1 = d < m1;
        const bool c2 = d < m2;
        const float nm2 = c1 ? m1 : (c2 ? d : m2);
        const int   ni2 = c1 ? i1 : (c2 ? idx : i2);
        m1 = c1 ? d : m1; i1 = c1 ? idx : i1;
        m2 = nm2; i2 = ni2;
      }
    }
  }

  // top-32: 1 barrier/round; DPP min; extraction promotes cached 2nd-min, rescan only if stale
  int myk_idx = 0; float myk_d = 0.0f; int k0_idx = 0;
  unsigned removed = 0u; bool have2 = true;
  for (int kk = 0; kk < K_; ++kk) {
    const int p = kk & 1;
    const unsigned key = f2key(m1);
    const unsigned kmin = dpp_umin_bcast(key);
    const int fl = __ffsll(__ballot(key == kmin)) - 1;
    if (lane == fl) { sval[p][t >> 6] = m1; sidx[p][t >> 6] = i1; }
    __syncthreads();
    float wv = sval[p][0]; int wi = sidx[p][0];
#pragma unroll
    for (int u = 1; u < 4; ++u) {
      const float v = sval[p][u]; const int ii = sidx[p][u];
      if (v < wv || (v == wv && ii < wi)) { wv = v; wi = ii; }
    }
    wi &= (N1_ - 1);
    if ((t >> 3) == kk) { myk_idx = wi; myk_d = wv; }
    if (kk == 0) k0_idx = wi;
    if (kk < K_ - 1 && t == (wi >> 5)) {
      removed |= 1u << (wi & 31);
      if (have2) { m1 = m2; i1 = i2; have2 = false; }
      else {
        m1 = FLTMAX; i1 = t*32; m2 = FLTMAX; i2 = t*32;
#pragma unroll
        for (int j = 0; j < 32; ++j) {
          const float d = ((removed >> j) & 1u) ? FLTMAX : d2v[j];
          const int idx = t*32 + j;
          const bool c1 = d < m1;
          const bool c2 = d < m2;
          const float nm2 = c1 ? m1 : (c2 ? d : m2);
          const int   ni2 = c1 ? i1 : (c2 ? idx : i2);
          m1 = c1 ? d : m1; i1 = c1 ? idx : i1;
          m2 = nm2; i2 = ni2;
        }
        have2 = true;
      }
    }
  }

  // -------- phase 2: gather h0, MLP (weights direct from global/L1), maxpool --------
  {
    const int k = t >> 3, fg = t & 7;
    int nk = myk_idx;
    if (myk_d > 0.04f) nk = k0_idx;        // ball-query radius clamp
    nk &= (N1_ - 1);
    const float* frow = feat + ((size_t)(b * N1_ + nk)) * F1_ + fg * 8;
    const float4 f0 = *(const float4*)frow;
    const float4 f1 = *(const float4*)(frow + 4);
    const int fb = 3 + fg * 8;
    buf0[(fb+0)*HSTR + k] = f0.x;
    buf0[(fb+1)*HSTR + k] = f0.y;
    buf0[(fb+2)*HSTR + k] = f0.z;
    buf0[(fb+3)*HSTR + k] = f0.w;
    buf0[(fb+4)*HSTR + k] = f1.x;
    buf0[(fb+5)*HSTR + k] = f1.y;
    buf0[(fb+6)*HSTR + k] = f1.z;
    buf0[(fb+7)*HSTR + k] = f1.w;
    if (fg < 3) {
      const float pc = gxyz[(size_t)nk * 3 + fg];
      const float qc = (fg == 0) ? qx : (fg == 1) ? qy : qz;
      buf0[fg * HSTR + k] = __fsub_rn(pc, qc);
    }
  }
  __syncthreads();

#define LEAKY_STORE2(acc, mi_, biasg, hout) { \
    const float bb = biasg[mg*2 + (mi_)]; \
    float4 v; \
    v.x = acc.x + bb; v.x = fmaxf(v.x, 0.2f*v.x); \
    v.y = acc.y + bb; v.y = fmaxf(v.y, 0.2f*v.y); \
    v.z = acc.z + bb; v.z = fmaxf(v.z, 0.2f*v.z); \
    v.w = acc.w + bb; v.w = fmaxf(v.w, 0.2f*v.w); \
    *(float4*)&hout[(mg*2 + (mi_)) * HSTR + kq * 4] = v; }

  // layer 1: 67 -> 64 (all 256 threads: 2m x 4k tiles; ascending-c order)
  {
    const int kq = t & 7, mg = t >> 3;   // mg 0..31
    float4 a0 = {0,0,0,0}, a1 = {0,0,0,0};
#pragma unroll 4
    for (int c = 0; c < CIN_; ++c) {
      const float2 wp = *(const float2*)&w0g[c * M1_ + mg * 2];
      const float4 h  = *(const float4*)&buf0[c * HSTR + kq * 4];
      a0.x += h.x*wp.x; a0.y += h.y*wp.x; a0.z += h.z*wp.x; a0.w += h.w*wp.x;
      a1.x += h.x*wp.y; a1.y += h.y*wp.y; a1.z += h.z*wp.y; a1.w += h.w*wp.y;
    }
    LEAKY_STORE2(a0, 0, b0g, buf1) LEAKY_STORE2(a1, 1, b0g, buf1)
  }
  __syncthreads();

  // layer 2: 64 -> 64
  {
    const int kq = t & 7, mg = t >> 3;
    float4 a0 = {0,0,0,0}, a1 = {0,0,0,0};
#pragma unroll 4
    for (int c = 0; c < M1_; ++c) {
      const float2 wp = *(const float2*)&w1g[c * M2_ + mg * 2];
      const float4 h  = *(const float4*)&buf1[c * HSTR + kq * 4];
      a0.x += h.x*wp.x; a0.y += h.y*wp.x; a0.z += h.z*wp.x; a0.w += h.w*wp.x;
      a1.x += h.x*wp.y; a1.y += h.y*wp.y; a1.z += h.z*wp.y; a1.w += h.w*wp.y;
    }
    LEAKY_STORE2(a0, 0, b1g, buf0) LEAKY_STORE2(a1, 1, b1g, buf0)
  }
#undef LEAKY_STORE2
  __syncthreads();

  // layer 3: 64 -> 128, + maxpool over k
  {
    const int kq = t & 7, mg = t >> 3;   // mg in 0..31
    float4 a0 = {0,0,0,0}, a1 = {0,0,0,0}, a2 = {0,0,0,0}, a3 = {0,0,0,0};
#pragma unroll 4
    for (int c = 0; c < M2_; ++c) {
      const float4 wp = *(const float4*)&w2g[c * M3_ + mg * 4];
      const float4 h  = *(const float4*)&buf0[c * HSTR + kq * 4];
      a0.x += h.x*wp.x; a0.y += h.y*wp.x; a0.z += h.z*wp.x; a0.w += h.w*wp.x;
      a1.x += h.x*wp.y; a1.y += h.y*wp.y; a1.z += h.z*wp.y; a1.w += h.w*wp.y;
      a2.x += h.x*wp.z; a2.y += h.y*wp.z; a2.z += h.z*wp.z; a2.w += h.w*wp.z;
      a3.x += h.x*wp.w; a3.y += h.y*wp.w; a3.z += h.z*wp.w; a3.w += h.w*wp.w;
    }
    float vm[4];
#define BIAS_LEAKY_HMAX(acc, mi_) { \
      const float bb = b2g[mg*4 + (mi_)]; \
      float vx = acc.x + bb; vx = fmaxf(vx, 0.2f*vx); \
      float vy = acc.y + bb; vy = fmaxf(vy, 0.2f*vy); \
      float vz = acc.z + bb; vz = fmaxf(vz, 0.2f*vz); \
      float vw = acc.w + bb; vw = fmaxf(vw, 0.2f*vw); \
      vm[mi_] = fmaxf(fmaxf(vx, vy), fmaxf(vz, vw)); }
    BIAS_LEAKY_HMAX(a0, 0) BIAS_LEAKY_HMAX(a1, 1) BIAS_LEAKY_HMAX(a2, 2) BIAS_LEAKY_HMAX(a3, 3)
#undef BIAS_LEAKY_HMAX
#pragma unroll
    for (int m = 1; m <= 4; m <<= 1) {
      vm[0] = fmaxf(vm[0], __shfl_xor(vm[0], m, 64));
      vm[1] = fmaxf(vm[1], __shfl_xor(vm[1], m, 64));
      vm[2] = fmaxf(vm[2], __shfl_xor(vm[2], m, 64));
      vm[3] = fmaxf(vm[3], __shfl_xor(vm[3], m, 64));
    }
    if (kq == 0) {
      float4 o; o.x = vm[0]; o.y = vm[1]; o.z = vm[2]; o.w = vm[3];
      *(float4*)&out_feat[(size_t)bq * M3_ + mg * 4] = o;   // overwrites this query's handshake words
    }
  }
}

extern "C" void kernel_launch(void* const* d_in, const int* in_sizes, int n_in,
                              void* d_out, int out_size, void* d_ws, size_t ws_size,
                              hipStream_t stream) {
  const float* xyz  = (const float*)d_in[0];
  const float* feat = (const float*)d_in[1];
  const float* w0   = (const float*)d_in[2];
  const float* b0   = (const float*)d_in[3];
  const float* w1   = (const float*)d_in[4];
  const float* b1   = (const float*)d_in[5];
  const float* w2   = (const float*)d_in[6];
  const float* b2   = (const float*)d_in[7];

  float* out_xyz  = (float*)d_out;                  // (8,1024,3) f32
  float* out_feat = out_xyz + B_ * N2_ * 3;         // (8,1024,128) f32

  fused_kernel<<<B_ + B_ * N2_, 256, 0, stream>>>(xyz, feat, w0, b0, w1, b1, w2, b2,
                                                  out_xyz, out_feat);
}